// Round 1
// baseline (902.832 us; speedup 1.0000x reference)
//
#include <hip/hip_runtime.h>
#include <hip/hip_bf16.h>

// GCN: 2-layer GCNConv with symmetric norm + self loops.
// N=100000 nodes, F=256, H=128, C=40, E=1600000 edges.
//
// Pipeline per launch (everything rebuilt each call; ws is re-poisoned):
//  1. CSR build keyed by dst: memset cnt -> histogram -> scan (3 kernels) -> fill
//     dinv[v] = rsqrt(in_deg(v)+1) computed during scan.
//  2. h0 = x @ W_pre + b_pre          (GEMM K=256, bias)
//  3. t  = h0 @ W1                    (GEMM K=128)
//     h1 = relu(gather-agg(t) + b1)   (wave-per-node CSR gather)
//  4. t  = h1 @ W2 ; h2 = relu(agg + b2)
//  5. out = log_softmax(h2 @ W_post + b_post)  (fused)

#define NFEAT 256
#define NHID  128
#define NCLASS 40

// ---------------- CSR build ----------------

__global__ void hist_kernel(const int* __restrict__ dst, int* __restrict__ cnt, int E) {
    int e = blockIdx.x * blockDim.x + threadIdx.x;
    if (e < E) atomicAdd(&cnt[dst[e]], 1);
}

__global__ __launch_bounds__(1024) void scan_block(const int* __restrict__ cnt,
                                                   int* __restrict__ rowptr,
                                                   int* __restrict__ bsum,
                                                   float* __restrict__ dinv, int N) {
    __shared__ int s[1024];
    int tid = threadIdx.x;
    int i = blockIdx.x * 1024 + tid;
    int v = (i < N) ? cnt[i] : 0;
    s[tid] = v;
    __syncthreads();
    #pragma unroll
    for (int off = 1; off < 1024; off <<= 1) {
        int t = (tid >= off) ? s[tid - off] : 0;
        __syncthreads();
        s[tid] += t;
        __syncthreads();
    }
    if (i < N) {
        rowptr[i] = s[tid] - v;                 // exclusive within block
        dinv[i] = rsqrtf((float)(v + 1));       // +1 self loop
    }
    if (tid == 1023) bsum[blockIdx.x] = s[tid];
}

__global__ void scan_tops(int* bsum, int nb) {
    __shared__ int s[128];
    int tid = threadIdx.x;
    int v = (tid < nb) ? bsum[tid] : 0;
    s[tid] = v;
    __syncthreads();
    for (int off = 1; off < 128; off <<= 1) {
        int t = (tid >= off) ? s[tid - off] : 0;
        __syncthreads();
        s[tid] += t;
        __syncthreads();
    }
    if (tid < nb) bsum[tid] = s[tid] - v;       // exclusive block offsets
}

__global__ __launch_bounds__(1024) void scan_add(int* __restrict__ rowptr,
                                                 const int* __restrict__ bsum,
                                                 int* __restrict__ cursor, int N, int E) {
    int i = blockIdx.x * 1024 + threadIdx.x;
    if (i < N) {
        int r = rowptr[i] + bsum[i >> 10];
        rowptr[i] = r;
        cursor[i] = r;
        if (i == 0) rowptr[N] = E;
    }
}

__global__ void fill_csr(const int* __restrict__ src, const int* __restrict__ dst,
                         int* __restrict__ cursor, int* __restrict__ col, int E) {
    int e = blockIdx.x * blockDim.x + threadIdx.x;
    if (e < E) {
        int d = dst[e];
        int pos = atomicAdd(&cursor[d], 1);
        col[pos] = src[e];
    }
}

// ---------------- GEMM: [N,K] x [K,128] (+bias) ----------------
// block = 256 threads, tile 64 rows x 128 cols.
// LDS: W chunk [64][128] (32KB) + X tile [64][64] (16KB) = 48KB.

template <int K, bool ADD_BIAS>
__global__ __launch_bounds__(256) void gemm_n128(const float* __restrict__ X,
                                                 const float* __restrict__ W,
                                                 const float* __restrict__ bias,
                                                 float* __restrict__ out, int N) {
    __shared__ float Ws[64 * 128];
    __shared__ float Xs[64 * 64];
    int tid = threadIdx.x;
    int tx = tid & 31;        // col group: cols tx*4 .. tx*4+3
    int ty = tid >> 5;        // row group: rows ty*8 .. ty*8+7
    int r0 = blockIdx.x * 64;

    float4 acc[8];
    #pragma unroll
    for (int r = 0; r < 8; r++) acc[r] = make_float4(0.f, 0.f, 0.f, 0.f);

    for (int k0 = 0; k0 < K; k0 += 64) {
        // stage W[k0..k0+64)[0..128): 2048 float4, 8 per thread
        #pragma unroll
        for (int i = 0; i < 8; i++) {
            int idx = tid + i * 256;
            int row = idx >> 5, c4 = idx & 31;
            ((float4*)Ws)[idx] = ((const float4*)(W + (size_t)(k0 + row) * 128))[c4];
        }
        // stage X[r0..r0+64)[k0..k0+64): 1024 float4, 4 per thread
        #pragma unroll
        for (int i = 0; i < 4; i++) {
            int idx = tid + i * 256;
            int row = idx >> 4, c4 = idx & 15;
            float4 v = make_float4(0.f, 0.f, 0.f, 0.f);
            if (r0 + row < N) v = ((const float4*)(X + (size_t)(r0 + row) * K + k0))[c4];
            ((float4*)Xs)[idx] = v;
        }
        __syncthreads();
        #pragma unroll 4
        for (int kk = 0; kk < 64; ++kk) {
            float4 b = ((const float4*)Ws)[kk * 32 + tx];
            #pragma unroll
            for (int r = 0; r < 8; r++) {
                float a = Xs[(ty * 8 + r) * 64 + kk];
                acc[r].x += a * b.x; acc[r].y += a * b.y;
                acc[r].z += a * b.z; acc[r].w += a * b.w;
            }
        }
        __syncthreads();
    }

    float4 bb = make_float4(0.f, 0.f, 0.f, 0.f);
    if (ADD_BIAS) bb = ((const float4*)bias)[tx];
    #pragma unroll
    for (int r = 0; r < 8; r++) {
        int row = r0 + ty * 8 + r;
        if (row < N) {
            float4 o = acc[r];
            if (ADD_BIAS) { o.x += bb.x; o.y += bb.y; o.z += bb.z; o.w += bb.w; }
            ((float4*)(out + (size_t)row * 128))[tx] = o;
        }
    }
}

// ---------------- CSR gather-aggregate (one wave per node) ----------------
// out[v] = dinv[v]^2 * t[v] + sum_e dinv[col[e]]*dinv[v]*t[col[e]] + bias ; optional relu

template <bool RELU>
__global__ __launch_bounds__(256) void aggregate(const float* __restrict__ t,
                                                 const int* __restrict__ rowptr,
                                                 const int* __restrict__ col,
                                                 const float* __restrict__ dinv,
                                                 const float* __restrict__ bias,
                                                 float* __restrict__ out, int N) {
    int gid = blockIdx.x * blockDim.x + threadIdx.x;
    int wid = gid >> 6;          // node id
    int lane = threadIdx.x & 63; // 2 floats per lane
    if (wid >= N) return;
    float dv = dinv[wid];
    int beg = rowptr[wid], end = rowptr[wid + 1];
    const float2* t2 = (const float2*)t;

    float2 self = t2[(size_t)wid * 64 + lane];
    float2 acc;
    float w0 = dv * dv;
    acc.x = w0 * self.x;
    acc.y = w0 * self.y;

    for (int e = beg; e < end; ++e) {
        int u = col[e];
        float w = dinv[u] * dv;
        float2 m = t2[(size_t)u * 64 + lane];
        acc.x += w * m.x;
        acc.y += w * m.y;
    }
    float2 bb = ((const float2*)bias)[lane];
    acc.x += bb.x; acc.y += bb.y;
    if (RELU) { acc.x = fmaxf(acc.x, 0.f); acc.y = fmaxf(acc.y, 0.f); }
    ((float2*)out)[(size_t)wid * 64 + lane] = acc;
}

// ---------------- fused post GEMM + log_softmax ----------------
// block 256: 64 rows/block, 4 lanes per row, 10 cols per lane.

__global__ __launch_bounds__(256) void post_softmax(const float* __restrict__ X,
                                                    const float* __restrict__ W,
                                                    const float* __restrict__ bias,
                                                    float* __restrict__ out, int N) {
    __shared__ float Ws[128 * 40];
    __shared__ float Xs[64 * 128];
    __shared__ float bs[40];
    int tid = threadIdx.x;
    int r0 = blockIdx.x * 64;

    #pragma unroll
    for (int i = 0; i < 5; i++)
        ((float4*)Ws)[tid + i * 256] = ((const float4*)W)[tid + i * 256];
    if (tid < 40) bs[tid] = bias[tid];
    #pragma unroll
    for (int i = 0; i < 8; i++) {
        int idx = tid + i * 256;
        int row = idx >> 5, c4 = idx & 31;
        float4 v = make_float4(0.f, 0.f, 0.f, 0.f);
        if (r0 + row < N) v = ((const float4*)(X + (size_t)(r0 + row) * 128))[c4];
        ((float4*)Xs)[idx] = v;
    }
    __syncthreads();

    int row = tid >> 2;        // 0..63
    int part = tid & 3;        // cols part*10 .. part*10+9
    float acc[10];
    #pragma unroll
    for (int c = 0; c < 10; c++) acc[c] = 0.f;
    for (int k = 0; k < 128; k++) {
        float a = Xs[row * 128 + k];
        #pragma unroll
        for (int c = 0; c < 10; c++) acc[c] += a * Ws[k * 40 + part * 10 + c];
    }
    #pragma unroll
    for (int c = 0; c < 10; c++) acc[c] += bs[part * 10 + c];

    float m = acc[0];
    #pragma unroll
    for (int c = 1; c < 10; c++) m = fmaxf(m, acc[c]);
    m = fmaxf(m, __shfl_xor(m, 1));
    m = fmaxf(m, __shfl_xor(m, 2));
    float s = 0.f;
    #pragma unroll
    for (int c = 0; c < 10; c++) s += __expf(acc[c] - m);
    s += __shfl_xor(s, 1);
    s += __shfl_xor(s, 2);
    float lse = m + __logf(s);

    int grow = r0 + row;
    if (grow < N) {
        #pragma unroll
        for (int c = 0; c < 10; c++)
            out[(size_t)grow * 40 + part * 10 + c] = acc[c] - lse;
    }
}

// ---------------- launch ----------------

extern "C" void kernel_launch(void* const* d_in, const int* in_sizes, int n_in,
                              void* d_out, int out_size, void* d_ws, size_t ws_size,
                              hipStream_t stream) {
    const int N = in_sizes[0] / NFEAT;   // 100000
    const int E = in_sizes[1] / 2;       // 1600000

    const float* x     = (const float*)d_in[0];
    const int*   ei    = (const int*)d_in[1];
    const int*   src   = ei;
    const int*   dst   = ei + E;
    const float* W_pre = (const float*)d_in[2];
    const float* b_pre = (const float*)d_in[3];
    const float* W1    = (const float*)d_in[4];
    const float* b1    = (const float*)d_in[5];
    const float* W2    = (const float*)d_in[6];
    const float* b2    = (const float*)d_in[7];
    const float* Wp    = (const float*)d_in[8];
    const float* bp    = (const float*)d_in[9];
    float* out = (float*)d_out;

    char* ws = (char*)d_ws;
    size_t off = 0;
    auto alloc = [&](size_t bytes) -> void* {
        off = (off + 255) & ~(size_t)255;
        void* p = ws + off;
        off += bytes;
        return p;
    };
    int*   cnt_cur = (int*)alloc((size_t)N * 4);          // histogram, later cursor
    int*   rowptr  = (int*)alloc((size_t)(N + 1) * 4);
    int*   bsum    = (int*)alloc(256 * 4);
    float* dinv    = (float*)alloc((size_t)N * 4);
    int*   colbuf  = (int*)alloc((size_t)E * 4);
    float* bufA    = (float*)alloc((size_t)N * NHID * 4);
    float* bufB    = (float*)alloc((size_t)N * NHID * 4);
    (void)ws_size;

    int nb = (N + 1023) / 1024;                 // 98 scan blocks
    int ge = (E + 255) / 256;                   // edge-grid
    int gg = (N + 63) / 64;                     // gemm grid (64 rows/block)
    int ga = ((size_t)N * 64 + 255) / 256;      // aggregate grid (wave/node)

    // 1. CSR build
    hipMemsetAsync(cnt_cur, 0, (size_t)N * 4, stream);
    hist_kernel<<<ge, 256, 0, stream>>>(dst, cnt_cur, E);
    scan_block<<<nb, 1024, 0, stream>>>(cnt_cur, rowptr, bsum, dinv, N);
    scan_tops<<<1, 128, 0, stream>>>(bsum, nb);
    scan_add<<<nb, 1024, 0, stream>>>(rowptr, bsum, cnt_cur, N, E);
    fill_csr<<<ge, 256, 0, stream>>>(src, dst, cnt_cur, colbuf, E);

    // 2. h0 = x @ W_pre + b_pre
    gemm_n128<NFEAT, true><<<gg, 256, 0, stream>>>(x, W_pre, b_pre, bufA, N);

    // 3. conv1
    gemm_n128<NHID, false><<<gg, 256, 0, stream>>>(bufA, W1, nullptr, bufB, N);
    aggregate<true><<<ga, 256, 0, stream>>>(bufB, rowptr, colbuf, dinv, b1, bufA, N);

    // 4. conv2
    gemm_n128<NHID, false><<<gg, 256, 0, stream>>>(bufA, W2, nullptr, bufB, N);
    aggregate<true><<<ga, 256, 0, stream>>>(bufB, rowptr, colbuf, dinv, b2, bufA, N);

    // 5. logits + log_softmax
    post_softmax<<<gg, 256, 0, stream>>>(bufA, Wp, bp, out, N);
}

// Round 3
// 777.118 us; speedup vs baseline: 1.1618x; 1.1618x over previous
//
#include <hip/hip_runtime.h>
#include <hip/hip_bf16.h>

// GCN: 2-layer GCNConv with symmetric norm + self loops.
// N=100000 nodes, F=256, H=128, C=40, E=1600000 edges.
//
// Round 2 (resubmit after infra timeout): hidden pipeline in bf16.
//  - weights cast+transposed to bf16 [C][K] on device (prep_weights)
//  - GEMMs via mfma_f32_16x16x32_bf16 (fp32 accum), epilogue writes bf16
//  - aggregate gathers bf16 rows (256 B/edge), fp32 accum, 2-deep pipeline
//  - final GEMM+log_softmax stays fp32 compute, reads bf16 h2

#define NFEAT 256
#define NHID  128
#define NCLASS 40

typedef __attribute__((ext_vector_type(8))) __bf16 bf16x8;
typedef __attribute__((ext_vector_type(4))) float f32x4;
typedef __attribute__((ext_vector_type(8))) unsigned short ushort8;

__device__ __forceinline__ unsigned short f2bf(float f) {
    unsigned int u = __builtin_bit_cast(unsigned int, f);
    u = (u + 0x7FFF + ((u >> 16) & 1)) >> 16;   // RNE
    return (unsigned short)u;
}
__device__ __forceinline__ float bf2f(unsigned short h) {
    unsigned int u = ((unsigned int)h) << 16;
    return __builtin_bit_cast(float, u);
}

// ---------------- CSR build ----------------

__global__ void hist_kernel(const int* __restrict__ dst, int* __restrict__ cnt, int E) {
    int e = blockIdx.x * blockDim.x + threadIdx.x;
    if (e < E) atomicAdd(&cnt[dst[e]], 1);
}

__global__ __launch_bounds__(1024) void scan_block(const int* __restrict__ cnt,
                                                   int* __restrict__ rowptr,
                                                   int* __restrict__ bsum,
                                                   float* __restrict__ dinv, int N) {
    __shared__ int s[1024];
    int tid = threadIdx.x;
    int i = blockIdx.x * 1024 + tid;
    int v = (i < N) ? cnt[i] : 0;
    s[tid] = v;
    __syncthreads();
    #pragma unroll
    for (int off = 1; off < 1024; off <<= 1) {
        int t = (tid >= off) ? s[tid - off] : 0;
        __syncthreads();
        s[tid] += t;
        __syncthreads();
    }
    if (i < N) {
        rowptr[i] = s[tid] - v;
        dinv[i] = rsqrtf((float)(v + 1));
    }
    if (tid == 1023) bsum[blockIdx.x] = s[tid];
}

__global__ void scan_tops(int* bsum, int nb) {
    __shared__ int s[128];
    int tid = threadIdx.x;
    int v = (tid < nb) ? bsum[tid] : 0;
    s[tid] = v;
    __syncthreads();
    for (int off = 1; off < 128; off <<= 1) {
        int t = (tid >= off) ? s[tid - off] : 0;
        __syncthreads();
        s[tid] += t;
        __syncthreads();
    }
    if (tid < nb) bsum[tid] = s[tid] - v;
}

__global__ __launch_bounds__(1024) void scan_add(int* __restrict__ rowptr,
                                                 const int* __restrict__ bsum,
                                                 int* __restrict__ cursor, int N, int E) {
    int i = blockIdx.x * 1024 + threadIdx.x;
    if (i < N) {
        int r = rowptr[i] + bsum[i >> 10];
        rowptr[i] = r;
        cursor[i] = r;
        if (i == 0) rowptr[N] = E;
    }
}

__global__ void fill_csr(const int* __restrict__ src, const int* __restrict__ dst,
                         int* __restrict__ cursor, int* __restrict__ col, int E) {
    int e = blockIdx.x * blockDim.x + threadIdx.x;
    if (e < E) {
        int d = dst[e];
        int pos = atomicAdd(&cursor[d], 1);
        col[pos] = src[e];
    }
}

// ---------------- weight prep: cast + transpose to bf16 [C][K] ----------------

__global__ void prep_weights(const float* __restrict__ Wpre, const float* __restrict__ W1,
                             const float* __restrict__ W2,
                             unsigned short* __restrict__ WpreT,
                             unsigned short* __restrict__ W1T,
                             unsigned short* __restrict__ W2T) {
    int id = blockIdx.x * blockDim.x + threadIdx.x;   // 65536 total
    if (id < 32768) {                                  // Wpre [256][128] -> [128][256]
        int k = id >> 7, c = id & 127;
        WpreT[c * 256 + k] = f2bf(Wpre[id]);
    } else if (id < 49152) {
        int t = id - 32768; int k = t >> 7, c = t & 127;
        W1T[c * 128 + k] = f2bf(W1[t]);
    } else if (id < 65536) {
        int t = id - 49152; int k = t >> 7, c = t & 127;
        W2T[c * 128 + k] = f2bf(W2[t]);
    }
}

// ---------------- MFMA GEMM: [N,K] x Wt[128][K] -> bf16 [N,128] ----------------
// block = 256 thr (4 waves); each wave 32 rows (2 mtiles of 16); block 128 rows.
// LDS: Wt chunk [128][128+8] bf16 (34.8 KB), staged per 128-wide K chunk.
// Fragment layouts (16x16x32 bf16, verified per guide):
//   A: lane holds A[l&15][8*(l>>4)+i], i=0..7 ; B: Wt row = out col, same pattern.
//   C: col = lane&15, row = (lane>>4)*4 + reg.

template <int K, bool AFLOAT, bool BIAS>
__global__ __launch_bounds__(256) void gemm_mfma(const void* __restrict__ Av,
                                                 const unsigned short* __restrict__ Wt,
                                                 const float* __restrict__ bias,
                                                 unsigned short* __restrict__ out,
                                                 int N) {
    __shared__ unsigned short Ws[128 * 136];
    int tid = threadIdx.x;
    int lane = tid & 63;
    int w = tid >> 6;
    int l15 = lane & 15;
    int lk = lane >> 4;                // 0..3
    int wrow = blockIdx.x * 128 + w * 32;

    f32x4 acc[2][8];
    #pragma unroll
    for (int mt = 0; mt < 2; mt++)
        #pragma unroll
        for (int nt = 0; nt < 8; nt++)
            acc[mt][nt] = (f32x4)0.f;

    #pragma unroll
    for (int c = 0; c < K / 128; ++c) {
        __syncthreads();
        // stage Wt chunk: 128 rows x 128 shorts, padded stride 136
        #pragma unroll
        for (int i = 0; i < 8; i++) {
            int v = tid + i * 256;
            int rowc = v >> 4, c16 = v & 15;
            *(ushort8*)&Ws[rowc * 136 + c16 * 8] =
                *(const ushort8*)&Wt[(size_t)rowc * K + c * 128 + c16 * 8];
        }
        __syncthreads();

        // A fragments from global
        bf16x8 af[2][4];
        #pragma unroll
        for (int mt = 0; mt < 2; mt++) {
            int r = wrow + mt * 16 + l15;
            bool ok = r < N;
            #pragma unroll
            for (int ks = 0; ks < 4; ks++) {
                int k = c * 128 + ks * 32 + lk * 8;
                if (AFLOAT) {
                    const float* ap = (const float*)Av + (size_t)r * K + k;
                    float4 x0 = make_float4(0.f, 0.f, 0.f, 0.f), x1 = x0;
                    if (ok) { x0 = *(const float4*)ap; x1 = *(const float4*)(ap + 4); }
                    ushort8 u;
                    u[0] = f2bf(x0.x); u[1] = f2bf(x0.y); u[2] = f2bf(x0.z); u[3] = f2bf(x0.w);
                    u[4] = f2bf(x1.x); u[5] = f2bf(x1.y); u[6] = f2bf(x1.z); u[7] = f2bf(x1.w);
                    af[mt][ks] = __builtin_bit_cast(bf16x8, u);
                } else {
                    const unsigned short* ap = (const unsigned short*)Av + (size_t)r * K + k;
                    ushort8 u = {};
                    if (ok) u = *(const ushort8*)ap;
                    af[mt][ks] = __builtin_bit_cast(bf16x8, u);
                }
            }
        }

        #pragma unroll
        for (int nt = 0; nt < 8; nt++) {
            bf16x8 bfr[4];
            #pragma unroll
            for (int ks = 0; ks < 4; ks++) {
                ushort8 u = *(const ushort8*)&Ws[(nt * 16 + l15) * 136 + ks * 32 + lk * 8];
                bfr[ks] = __builtin_bit_cast(bf16x8, u);
            }
            #pragma unroll
            for (int ks = 0; ks < 4; ks++) {
                acc[0][nt] = __builtin_amdgcn_mfma_f32_16x16x32_bf16(af[0][ks], bfr[ks], acc[0][nt], 0, 0, 0);
                acc[1][nt] = __builtin_amdgcn_mfma_f32_16x16x32_bf16(af[1][ks], bfr[ks], acc[1][nt], 0, 0, 0);
            }
        }
    }

    // epilogue: +bias, write bf16
    #pragma unroll
    for (int nt = 0; nt < 8; nt++) {
        int colc = nt * 16 + l15;
        float bv = BIAS ? bias[colc] : 0.f;
        #pragma unroll
        for (int mt = 0; mt < 2; mt++) {
            #pragma unroll
            for (int j = 0; j < 4; j++) {
                int r = wrow + mt * 16 + lk * 4 + j;
                if (r < N)
                    out[(size_t)r * 128 + colc] = f2bf(acc[mt][nt][j] + bv);
            }
        }
    }
}

// ---------------- CSR gather-aggregate (wave per node, bf16 rows) ----------------
// out[v] = relu( dinv[v]^2 * t[v] + sum_e dinv[u]*dinv[v]*t[u] + bias )

__global__ __launch_bounds__(256) void aggregate_bf16(const unsigned short* __restrict__ t,
                                                      const int* __restrict__ rowptr,
                                                      const int* __restrict__ col,
                                                      const float* __restrict__ dinv,
                                                      const float* __restrict__ bias,
                                                      unsigned short* __restrict__ out,
                                                      int N) {
    int gid = blockIdx.x * blockDim.x + threadIdx.x;
    int wid = gid >> 6;          // node
    int lane = threadIdx.x & 63; // 2 bf16 per lane
    if (wid >= N) return;
    float dv = dinv[wid];
    int beg = rowptr[wid], end = rowptr[wid + 1];
    const unsigned int* t2 = (const unsigned int*)t;

    unsigned int s = t2[(size_t)wid * 64 + lane];
    float w0 = dv * dv;
    float accx = w0 * bf2f((unsigned short)(s & 0xffff));
    float accy = w0 * __builtin_bit_cast(float, s & 0xffff0000u);

    int e = beg;
    float du_n = 0.f;
    unsigned int m_n = 0;
    if (e < end) {
        int u = col[e];
        du_n = dinv[u];
        m_n = t2[(size_t)u * 64 + lane];
    }
    while (e < end) {
        float du = du_n;
        unsigned int m = m_n;
        int en = e + 1;
        if (en < end) {
            int u = col[en];
            du_n = dinv[u];
            m_n = t2[(size_t)u * 64 + lane];
        }
        float wgt = du * dv;
        accx += wgt * bf2f((unsigned short)(m & 0xffff));
        accy += wgt * __builtin_bit_cast(float, m & 0xffff0000u);
        e = en;
    }
    float2 bb = ((const float2*)bias)[lane];
    accx = fmaxf(accx + bb.x, 0.f);
    accy = fmaxf(accy + bb.y, 0.f);
    unsigned int o = (unsigned int)f2bf(accx) | ((unsigned int)f2bf(accy) << 16);
    ((unsigned int*)out)[(size_t)wid * 64 + lane] = o;
}

// ---------------- fused post GEMM + log_softmax (fp32 compute, bf16 X) ----------------

__global__ __launch_bounds__(256) void post_softmax(const unsigned short* __restrict__ Xb,
                                                    const float* __restrict__ W,
                                                    const float* __restrict__ bias,
                                                    float* __restrict__ out, int N) {
    __shared__ float Ws[128 * 40];
    __shared__ float Xs[64 * 128];
    __shared__ float bs[40];
    int tid = threadIdx.x;
    int r0 = blockIdx.x * 64;

    #pragma unroll
    for (int i = 0; i < 5; i++)
        ((float4*)Ws)[tid + i * 256] = ((const float4*)W)[tid + i * 256];
    if (tid < 40) bs[tid] = bias[tid];
    #pragma unroll
    for (int i = 0; i < 4; i++) {
        int v = tid + i * 256;
        int row = v >> 4, c8 = v & 15;
        ushort8 u = {};
        if (r0 + row < N) u = *(const ushort8*)&Xb[(size_t)(r0 + row) * 128 + c8 * 8];
        #pragma unroll
        for (int j = 0; j < 8; j++) Xs[row * 128 + c8 * 8 + j] = bf2f(u[j]);
    }
    __syncthreads();

    int row = tid >> 2;
    int part = tid & 3;
    float acc[10];
    #pragma unroll
    for (int c = 0; c < 10; c++) acc[c] = 0.f;
    for (int k = 0; k < 128; k++) {
        float a = Xs[row * 128 + k];
        #pragma unroll
        for (int c = 0; c < 10; c++) acc[c] += a * Ws[k * 40 + part * 10 + c];
    }
    #pragma unroll
    for (int c = 0; c < 10; c++) acc[c] += bs[part * 10 + c];

    float m = acc[0];
    #pragma unroll
    for (int c = 1; c < 10; c++) m = fmaxf(m, acc[c]);
    m = fmaxf(m, __shfl_xor(m, 1));
    m = fmaxf(m, __shfl_xor(m, 2));
    float s = 0.f;
    #pragma unroll
    for (int c = 0; c < 10; c++) s += __expf(acc[c] - m);
    s += __shfl_xor(s, 1);
    s += __shfl_xor(s, 2);
    float lse = m + __logf(s);

    int grow = r0 + row;
    if (grow < N) {
        #pragma unroll
        for (int c = 0; c < 10; c++)
            out[(size_t)grow * 40 + part * 10 + c] = acc[c] - lse;
    }
}

// ---------------- launch ----------------

extern "C" void kernel_launch(void* const* d_in, const int* in_sizes, int n_in,
                              void* d_out, int out_size, void* d_ws, size_t ws_size,
                              hipStream_t stream) {
    const int N = in_sizes[0] / NFEAT;   // 100000
    const int E = in_sizes[1] / 2;       // 1600000

    const float* x     = (const float*)d_in[0];
    const int*   ei    = (const int*)d_in[1];
    const int*   src   = ei;
    const int*   dst   = ei + E;
    const float* W_pre = (const float*)d_in[2];
    const float* b_pre = (const float*)d_in[3];
    const float* W1    = (const float*)d_in[4];
    const float* b1    = (const float*)d_in[5];
    const float* W2    = (const float*)d_in[6];
    const float* b2    = (const float*)d_in[7];
    const float* Wp    = (const float*)d_in[8];
    const float* bp    = (const float*)d_in[9];
    float* out = (float*)d_out;

    char* ws = (char*)d_ws;
    size_t off = 0;
    auto alloc = [&](size_t bytes) -> void* {
        off = (off + 255) & ~(size_t)255;
        void* p = ws + off;
        off += bytes;
        return p;
    };
    int*   cnt_cur = (int*)alloc((size_t)N * 4);
    int*   rowptr  = (int*)alloc((size_t)(N + 1) * 4);
    int*   bsum    = (int*)alloc(256 * 4);
    float* dinv    = (float*)alloc((size_t)N * 4);
    int*   colbuf  = (int*)alloc((size_t)E * 4);
    unsigned short* WpreT = (unsigned short*)alloc((size_t)NFEAT * NHID * 2);
    unsigned short* W1T   = (unsigned short*)alloc((size_t)NHID * NHID * 2);
    unsigned short* W2T   = (unsigned short*)alloc((size_t)NHID * NHID * 2);
    unsigned short* bufA  = (unsigned short*)alloc((size_t)N * NHID * 2);
    unsigned short* bufB  = (unsigned short*)alloc((size_t)N * NHID * 2);
    (void)ws_size;

    int nb = (N + 1023) / 1024;
    int ge = (E + 255) / 256;
    int gm = (N + 127) / 128;                   // mfma gemm grid
    int ga = (int)(((size_t)N * 64 + 255) / 256);
    int gp = (N + 63) / 64;

    // 1. CSR build + weight prep
    hipMemsetAsync(cnt_cur, 0, (size_t)N * 4, stream);
    hist_kernel<<<ge, 256, 0, stream>>>(dst, cnt_cur, E);
    scan_block<<<nb, 1024, 0, stream>>>(cnt_cur, rowptr, bsum, dinv, N);
    scan_tops<<<1, 128, 0, stream>>>(bsum, nb);
    scan_add<<<nb, 1024, 0, stream>>>(rowptr, bsum, cnt_cur, N, E);
    fill_csr<<<ge, 256, 0, stream>>>(src, dst, cnt_cur, colbuf, E);
    prep_weights<<<256, 256, 0, stream>>>(W_pre, W1, W2, WpreT, W1T, W2T);

    // 2. h0 = x @ W_pre + b_pre  (fp32 in, bf16 out)
    gemm_mfma<NFEAT, true, true><<<gm, 256, 0, stream>>>(x, WpreT, b_pre, bufA, N);

    // 3. conv1
    gemm_mfma<NHID, false, false><<<gm, 256, 0, stream>>>(bufA, W1T, nullptr, bufB, N);
    aggregate_bf16<<<ga, 256, 0, stream>>>(bufB, rowptr, colbuf, dinv, b1, bufA, N);

    // 4. conv2
    gemm_mfma<NHID, false, false><<<gm, 256, 0, stream>>>(bufA, W2T, nullptr, bufB, N);
    aggregate_bf16<<<ga, 256, 0, stream>>>(bufB, rowptr, colbuf, dinv, b2, bufA, N);

    // 5. logits + log_softmax
    post_softmax<<<gp, 256, 0, stream>>>(bufA, Wp, bp, out, N);
}

// Round 4
// 561.946 us; speedup vs baseline: 1.6066x; 1.3829x over previous
//
#include <hip/hip_runtime.h>
#include <hip/hip_bf16.h>

// GCN: 2-layer GCNConv with symmetric norm + self loops.
// N=100000 nodes, F=256, H=128, C=40, E=1600000 edges.
//
// Round 4:
//  - aggregate: 4-way edge-parallel wave (4 groups x 16 lanes, full row per
//    group, shfl_xor butterfly combine) -> 4x memory-level parallelism
//  - post GEMM+log_softmax via MFMA, B-frags in registers, no LDS
//  - rest unchanged from round 3 (bf16 hidden pipeline, MFMA GEMMs)

#define NFEAT 256
#define NHID  128
#define NCLASS 40

typedef __attribute__((ext_vector_type(8))) __bf16 bf16x8;
typedef __attribute__((ext_vector_type(4))) float f32x4;
typedef __attribute__((ext_vector_type(8))) unsigned short ushort8;

__device__ __forceinline__ unsigned short f2bf(float f) {
    unsigned int u = __builtin_bit_cast(unsigned int, f);
    u = (u + 0x7FFF + ((u >> 16) & 1)) >> 16;   // RNE
    return (unsigned short)u;
}
__device__ __forceinline__ float bf2f(unsigned short h) {
    unsigned int u = ((unsigned int)h) << 16;
    return __builtin_bit_cast(float, u);
}

// ---------------- CSR build ----------------

__global__ void hist_kernel(const int* __restrict__ dst, int* __restrict__ cnt, int E) {
    int e = blockIdx.x * blockDim.x + threadIdx.x;
    if (e < E) atomicAdd(&cnt[dst[e]], 1);
}

__global__ __launch_bounds__(1024) void scan_block(const int* __restrict__ cnt,
                                                   int* __restrict__ rowptr,
                                                   int* __restrict__ bsum,
                                                   float* __restrict__ dinv, int N) {
    __shared__ int s[1024];
    int tid = threadIdx.x;
    int i = blockIdx.x * 1024 + tid;
    int v = (i < N) ? cnt[i] : 0;
    s[tid] = v;
    __syncthreads();
    #pragma unroll
    for (int off = 1; off < 1024; off <<= 1) {
        int t = (tid >= off) ? s[tid - off] : 0;
        __syncthreads();
        s[tid] += t;
        __syncthreads();
    }
    if (i < N) {
        rowptr[i] = s[tid] - v;
        dinv[i] = rsqrtf((float)(v + 1));
    }
    if (tid == 1023) bsum[blockIdx.x] = s[tid];
}

__global__ void scan_tops(int* bsum, int nb) {
    __shared__ int s[128];
    int tid = threadIdx.x;
    int v = (tid < nb) ? bsum[tid] : 0;
    s[tid] = v;
    __syncthreads();
    for (int off = 1; off < 128; off <<= 1) {
        int t = (tid >= off) ? s[tid - off] : 0;
        __syncthreads();
        s[tid] += t;
        __syncthreads();
    }
    if (tid < nb) bsum[tid] = s[tid] - v;
}

__global__ __launch_bounds__(1024) void scan_add(int* __restrict__ rowptr,
                                                 const int* __restrict__ bsum,
                                                 int* __restrict__ cursor, int N, int E) {
    int i = blockIdx.x * 1024 + threadIdx.x;
    if (i < N) {
        int r = rowptr[i] + bsum[i >> 10];
        rowptr[i] = r;
        cursor[i] = r;
        if (i == 0) rowptr[N] = E;
    }
}

__global__ void fill_csr(const int* __restrict__ src, const int* __restrict__ dst,
                         int* __restrict__ cursor, int* __restrict__ col, int E) {
    int e = blockIdx.x * blockDim.x + threadIdx.x;
    if (e < E) {
        int d = dst[e];
        int pos = atomicAdd(&cursor[d], 1);
        col[pos] = src[e];
    }
}

// -------- weight prep: cast + transpose to bf16 [C][K]; Wp padded to 48 cols --------

__global__ void prep_weights(const float* __restrict__ Wpre, const float* __restrict__ W1,
                             const float* __restrict__ W2, const float* __restrict__ Wp,
                             unsigned short* __restrict__ WpreT,
                             unsigned short* __restrict__ W1T,
                             unsigned short* __restrict__ W2T,
                             unsigned short* __restrict__ WpT) {
    int id = blockIdx.x * blockDim.x + threadIdx.x;   // 71680 total
    if (id < 32768) {                                  // Wpre [256][128] -> [128][256]
        int k = id >> 7, c = id & 127;
        WpreT[c * 256 + k] = f2bf(Wpre[id]);
    } else if (id < 49152) {
        int t = id - 32768; int k = t >> 7, c = t & 127;
        W1T[c * 128 + k] = f2bf(W1[t]);
    } else if (id < 65536) {
        int t = id - 49152; int k = t >> 7, c = t & 127;
        W2T[c * 128 + k] = f2bf(W2[t]);
    } else if (id < 71680) {                           // Wp [128][40] -> [48][128], zero-pad
        int t = id - 65536; int c = t >> 7, k = t & 127;
        WpT[c * 128 + k] = (c < 40) ? f2bf(Wp[k * 40 + c]) : (unsigned short)0;
    }
}

// ---------------- MFMA GEMM: [N,K] x Wt[128][K] -> bf16 [N,128] ----------------

template <int K, bool AFLOAT, bool BIAS>
__global__ __launch_bounds__(256) void gemm_mfma(const void* __restrict__ Av,
                                                 const unsigned short* __restrict__ Wt,
                                                 const float* __restrict__ bias,
                                                 unsigned short* __restrict__ out,
                                                 int N) {
    __shared__ unsigned short Ws[128 * 136];
    int tid = threadIdx.x;
    int lane = tid & 63;
    int w = tid >> 6;
    int l15 = lane & 15;
    int lk = lane >> 4;                // 0..3
    int wrow = blockIdx.x * 128 + w * 32;

    f32x4 acc[2][8];
    #pragma unroll
    for (int mt = 0; mt < 2; mt++)
        #pragma unroll
        for (int nt = 0; nt < 8; nt++)
            acc[mt][nt] = (f32x4)0.f;

    #pragma unroll
    for (int c = 0; c < K / 128; ++c) {
        __syncthreads();
        #pragma unroll
        for (int i = 0; i < 8; i++) {
            int v = tid + i * 256;
            int rowc = v >> 4, c16 = v & 15;
            *(ushort8*)&Ws[rowc * 136 + c16 * 8] =
                *(const ushort8*)&Wt[(size_t)rowc * K + c * 128 + c16 * 8];
        }
        __syncthreads();

        bf16x8 af[2][4];
        #pragma unroll
        for (int mt = 0; mt < 2; mt++) {
            int r = wrow + mt * 16 + l15;
            bool ok = r < N;
            #pragma unroll
            for (int ks = 0; ks < 4; ks++) {
                int k = c * 128 + ks * 32 + lk * 8;
                if (AFLOAT) {
                    const float* ap = (const float*)Av + (size_t)r * K + k;
                    float4 x0 = make_float4(0.f, 0.f, 0.f, 0.f), x1 = x0;
                    if (ok) { x0 = *(const float4*)ap; x1 = *(const float4*)(ap + 4); }
                    ushort8 u;
                    u[0] = f2bf(x0.x); u[1] = f2bf(x0.y); u[2] = f2bf(x0.z); u[3] = f2bf(x0.w);
                    u[4] = f2bf(x1.x); u[5] = f2bf(x1.y); u[6] = f2bf(x1.z); u[7] = f2bf(x1.w);
                    af[mt][ks] = __builtin_bit_cast(bf16x8, u);
                } else {
                    const unsigned short* ap = (const unsigned short*)Av + (size_t)r * K + k;
                    ushort8 u = {};
                    if (ok) u = *(const ushort8*)ap;
                    af[mt][ks] = __builtin_bit_cast(bf16x8, u);
                }
            }
        }

        #pragma unroll
        for (int nt = 0; nt < 8; nt++) {
            bf16x8 bfr[4];
            #pragma unroll
            for (int ks = 0; ks < 4; ks++) {
                ushort8 u = *(const ushort8*)&Ws[(nt * 16 + l15) * 136 + ks * 32 + lk * 8];
                bfr[ks] = __builtin_bit_cast(bf16x8, u);
            }
            #pragma unroll
            for (int ks = 0; ks < 4; ks++) {
                acc[0][nt] = __builtin_amdgcn_mfma_f32_16x16x32_bf16(af[0][ks], bfr[ks], acc[0][nt], 0, 0, 0);
                acc[1][nt] = __builtin_amdgcn_mfma_f32_16x16x32_bf16(af[1][ks], bfr[ks], acc[1][nt], 0, 0, 0);
            }
        }
    }

    #pragma unroll
    for (int nt = 0; nt < 8; nt++) {
        int colc = nt * 16 + l15;
        float bv = BIAS ? bias[colc] : 0.f;
        #pragma unroll
        for (int mt = 0; mt < 2; mt++) {
            #pragma unroll
            for (int j = 0; j < 4; j++) {
                int r = wrow + mt * 16 + lk * 4 + j;
                if (r < N)
                    out[(size_t)r * 128 + colc] = f2bf(acc[mt][nt][j] + bv);
            }
        }
    }
}

// ------------- CSR gather-aggregate: wave/node, 4-way edge-parallel -------------
// 4 groups x 16 lanes; each group covers the full 128-col row (ushort8/lane)
// and processes edges e = beg+g, beg+g+4, ... ; butterfly combine at the end.

__global__ __launch_bounds__(256) void aggregate_bf16(const unsigned short* __restrict__ t,
                                                      const int* __restrict__ rowptr,
                                                      const int* __restrict__ col,
                                                      const float* __restrict__ dinv,
                                                      const float* __restrict__ bias,
                                                      unsigned short* __restrict__ out,
                                                      int N) {
    int gid = blockIdx.x * blockDim.x + threadIdx.x;
    int wid = gid >> 6;          // node
    if (wid >= N) return;
    int lane = threadIdx.x & 63;
    int g  = lane >> 4;          // edge group 0..3
    int sl = lane & 15;          // covers cols sl*8 .. sl*8+7

    float dv = dinv[wid];
    int beg = rowptr[wid], end = rowptr[wid + 1];

    float acc[8];
    #pragma unroll
    for (int i = 0; i < 8; i++) acc[i] = 0.f;

    if (g == 0) {
        ushort8 s = *(const ushort8*)&t[(size_t)wid * 128 + sl * 8];
        float w0 = dv * dv;
        #pragma unroll
        for (int i = 0; i < 8; i++) acc[i] = w0 * bf2f(s[i]);
    }

    int e = beg + g;
    int u = 0;
    if (e < end) u = col[e];
    while (e < end) {
        float du = dinv[u];
        ushort8 m = *(const ushort8*)&t[(size_t)u * 128 + sl * 8];
        int e2 = e + 4;
        if (e2 < end) u = col[e2];          // prefetch next col while row loads
        float wgt = du * dv;
        #pragma unroll
        for (int i = 0; i < 8; i++) acc[i] += wgt * bf2f(m[i]);
        e = e2;
    }

    // combine the 4 groups (lanes sl, sl+16, sl+32, sl+48)
    #pragma unroll
    for (int i = 0; i < 8; i++) {
        acc[i] += __shfl_xor(acc[i], 16);
        acc[i] += __shfl_xor(acc[i], 32);
    }

    if (g == 0) {
        float4 b0 = *(const float4*)&bias[sl * 8];
        float4 b1 = *(const float4*)&bias[sl * 8 + 4];
        float bb[8] = {b0.x, b0.y, b0.z, b0.w, b1.x, b1.y, b1.z, b1.w};
        ushort8 o;
        #pragma unroll
        for (int i = 0; i < 8; i++) o[i] = f2bf(fmaxf(acc[i] + bb[i], 0.f));
        *(ushort8*)&out[(size_t)wid * 128 + sl * 8] = o;
    }
}

// -------- fused post GEMM (MFMA, B in regs) + in-register log_softmax --------
// block 256 = 4 waves x 32 rows = 128 rows/block. WpT: bf16 [48][128].
// C frag: col = l15 (tile nt), row = mt*16 + lk*4 + j.

__global__ __launch_bounds__(256) void post_mfma(const unsigned short* __restrict__ Xb,
                                                 const unsigned short* __restrict__ WpT,
                                                 const float* __restrict__ bp,
                                                 float* __restrict__ out, int N) {
    int tid = threadIdx.x;
    int lane = tid & 63;
    int w = tid >> 6;
    int l15 = lane & 15;
    int lk = lane >> 4;
    int wrow = blockIdx.x * 128 + w * 32;

    // B fragments in registers: 3 col-tiles x 4 k-slices
    bf16x8 bfr[3][4];
    #pragma unroll
    for (int nt = 0; nt < 3; nt++)
        #pragma unroll
        for (int ks = 0; ks < 4; ks++)
            bfr[nt][ks] = __builtin_bit_cast(bf16x8,
                *(const ushort8*)&WpT[(size_t)(nt * 16 + l15) * 128 + ks * 32 + lk * 8]);

    float bv[3];
    #pragma unroll
    for (int nt = 0; nt < 3; nt++) {
        int c = nt * 16 + l15;
        bv[nt] = (c < NCLASS) ? bp[c] : 0.f;
    }

    f32x4 acc[2][3];
    #pragma unroll
    for (int mt = 0; mt < 2; mt++)
        #pragma unroll
        for (int nt = 0; nt < 3; nt++)
            acc[mt][nt] = (f32x4)0.f;

    #pragma unroll
    for (int mt = 0; mt < 2; mt++) {
        int r = wrow + mt * 16 + l15;
        bool ok = r < N;
        #pragma unroll
        for (int ks = 0; ks < 4; ks++) {
            ushort8 u = {};
            if (ok) u = *(const ushort8*)&Xb[(size_t)r * 128 + ks * 32 + lk * 8];
            bf16x8 af = __builtin_bit_cast(bf16x8, u);
            #pragma unroll
            for (int nt = 0; nt < 3; nt++)
                acc[mt][nt] = __builtin_amdgcn_mfma_f32_16x16x32_bf16(af, bfr[nt][ks], acc[mt][nt], 0, 0, 0);
        }
    }

    bool v2 = l15 < 8;   // tile 2 valid cols: 32..39
    #pragma unroll
    for (int mt = 0; mt < 2; mt++) {
        #pragma unroll
        for (int j = 0; j < 4; j++) {
            float a0 = acc[mt][0][j] + bv[0];
            float a1 = acc[mt][1][j] + bv[1];
            float a2 = v2 ? (acc[mt][2][j] + bv[2]) : -1e30f;
            float m = fmaxf(fmaxf(a0, a1), a2);
            m = fmaxf(m, __shfl_xor(m, 1));
            m = fmaxf(m, __shfl_xor(m, 2));
            m = fmaxf(m, __shfl_xor(m, 4));
            m = fmaxf(m, __shfl_xor(m, 8));
            float s = __expf(a0 - m) + __expf(a1 - m) + (v2 ? __expf(a2 - m) : 0.f);
            s += __shfl_xor(s, 1);
            s += __shfl_xor(s, 2);
            s += __shfl_xor(s, 4);
            s += __shfl_xor(s, 8);
            float lse = m + __logf(s);
            int r = wrow + mt * 16 + lk * 4 + j;
            if (r < N) {
                out[(size_t)r * 40 + l15]      = a0 - lse;
                out[(size_t)r * 40 + 16 + l15] = a1 - lse;
                if (v2) out[(size_t)r * 40 + 32 + l15] = a2 - lse;
            }
        }
    }
}

// ---------------- launch ----------------

extern "C" void kernel_launch(void* const* d_in, const int* in_sizes, int n_in,
                              void* d_out, int out_size, void* d_ws, size_t ws_size,
                              hipStream_t stream) {
    const int N = in_sizes[0] / NFEAT;   // 100000
    const int E = in_sizes[1] / 2;       // 1600000

    const float* x     = (const float*)d_in[0];
    const int*   ei    = (const int*)d_in[1];
    const int*   src   = ei;
    const int*   dst   = ei + E;
    const float* W_pre = (const float*)d_in[2];
    const float* b_pre = (const float*)d_in[3];
    const float* W1    = (const float*)d_in[4];
    const float* b1    = (const float*)d_in[5];
    const float* W2    = (const float*)d_in[6];
    const float* b2    = (const float*)d_in[7];
    const float* Wp    = (const float*)d_in[8];
    const float* bp    = (const float*)d_in[9];
    float* out = (float*)d_out;

    char* ws = (char*)d_ws;
    size_t off = 0;
    auto alloc = [&](size_t bytes) -> void* {
        off = (off + 255) & ~(size_t)255;
        void* p = ws + off;
        off += bytes;
        return p;
    };
    int*   cnt_cur = (int*)alloc((size_t)N * 4);
    int*   rowptr  = (int*)alloc((size_t)(N + 1) * 4);
    int*   bsum    = (int*)alloc(256 * 4);
    float* dinv    = (float*)alloc((size_t)N * 4);
    int*   colbuf  = (int*)alloc((size_t)E * 4);
    unsigned short* WpreT = (unsigned short*)alloc((size_t)NFEAT * NHID * 2);
    unsigned short* W1T   = (unsigned short*)alloc((size_t)NHID * NHID * 2);
    unsigned short* W2T   = (unsigned short*)alloc((size_t)NHID * NHID * 2);
    unsigned short* WpT   = (unsigned short*)alloc((size_t)48 * NHID * 2);
    unsigned short* bufA  = (unsigned short*)alloc((size_t)N * NHID * 2);
    unsigned short* bufB  = (unsigned short*)alloc((size_t)N * NHID * 2);
    (void)ws_size;

    int nb = (N + 1023) / 1024;
    int ge = (E + 255) / 256;
    int gm = (N + 127) / 128;
    int ga = (int)(((size_t)N * 64 + 255) / 256);

    // 1. CSR build + weight prep
    hipMemsetAsync(cnt_cur, 0, (size_t)N * 4, stream);
    hist_kernel<<<ge, 256, 0, stream>>>(dst, cnt_cur, E);
    scan_block<<<nb, 1024, 0, stream>>>(cnt_cur, rowptr, bsum, dinv, N);
    scan_tops<<<1, 128, 0, stream>>>(bsum, nb);
    scan_add<<<nb, 1024, 0, stream>>>(rowptr, bsum, cnt_cur, N, E);
    fill_csr<<<ge, 256, 0, stream>>>(src, dst, cnt_cur, colbuf, E);
    prep_weights<<<280, 256, 0, stream>>>(W_pre, W1, W2, Wp, WpreT, W1T, W2T, WpT);

    // 2. h0 = x @ W_pre + b_pre  (fp32 in, bf16 out)
    gemm_mfma<NFEAT, true, true><<<gm, 256, 0, stream>>>(x, WpreT, b_pre, bufA, N);

    // 3. conv1
    gemm_mfma<NHID, false, false><<<gm, 256, 0, stream>>>(bufA, W1T, nullptr, bufB, N);
    aggregate_bf16<<<ga, 256, 0, stream>>>(bufB, rowptr, colbuf, dinv, b1, bufA, N);

    // 4. conv2
    gemm_mfma<NHID, false, false><<<gm, 256, 0, stream>>>(bufA, W2T, nullptr, bufB, N);
    aggregate_bf16<<<ga, 256, 0, stream>>>(bufB, rowptr, colbuf, dinv, b2, bufA, N);

    // 5. logits + log_softmax (MFMA, no LDS)
    post_mfma<<<gm, 256, 0, stream>>>(bufA, WpT, bp, out, N);
}

// Round 6
// 436.175 us; speedup vs baseline: 2.0699x; 1.2883x over previous
//
#include <hip/hip_runtime.h>
#include <hip/hip_bf16.h>

// GCN: 2-layer GCNConv with symmetric norm + self loops.
// N=100000 nodes, F=256, H=128, C=40, E=1600000 edges.
//
// Round 5 (resubmit after infra timeout):
//  - CSR build rewritten as bucketed counting sort (bucket=dst>>9):
//    bucket_count -> bucket_scan -> bucket_scatter (LDS-staged, line-sized
//    run writes; kills fill_csr's 16x write amplification) -> csr_finalize
//    (per-bucket rowptr/dinv/col, sequential writes; absorbs hist+scan).
//  - aggregate: 2-deep row pipeline per 16-lane group (8 rows in flight/wave)
//  - MFMA GEMMs, bf16 hidden pipeline, MFMA post+log_softmax unchanged.

#define NFEAT 256
#define NHID  128
#define NCLASS 40

#define BSH   9              // 512 dsts per bucket
#define CHUNK 8192           // edges staged per scatter block

typedef __attribute__((ext_vector_type(8))) __bf16 bf16x8;
typedef __attribute__((ext_vector_type(4))) float f32x4;
typedef __attribute__((ext_vector_type(8))) unsigned short ushort8;

__device__ __forceinline__ unsigned short f2bf(float f) {
    unsigned int u = __builtin_bit_cast(unsigned int, f);
    u = (u + 0x7FFF + ((u >> 16) & 1)) >> 16;   // RNE
    return (unsigned short)u;
}
__device__ __forceinline__ float bf2f(unsigned short h) {
    unsigned int u = ((unsigned int)h) << 16;
    return __builtin_bit_cast(float, u);
}

// ---------------- CSR build (bucketed) ----------------

__global__ __launch_bounds__(256) void bucket_count(const int* __restrict__ dst,
                                                    int* __restrict__ bcnt, int E, int nbk) {
    __shared__ int h[256];
    int tid = threadIdx.x;
    h[tid] = 0;
    __syncthreads();
    for (int e = blockIdx.x * 256 + tid; e < E; e += gridDim.x * 256)
        atomicAdd(&h[dst[e] >> BSH], 1);
    __syncthreads();
    if (tid < nbk && h[tid]) atomicAdd(&bcnt[tid], h[tid]);
}

__global__ __launch_bounds__(256) void bucket_scan(const int* __restrict__ bcnt,
                                                   int* __restrict__ boff,
                                                   int* __restrict__ bcur, int nbk, int E) {
    __shared__ int s[256];
    int tid = threadIdx.x;
    int v = (tid < nbk) ? bcnt[tid] : 0;
    s[tid] = v;
    __syncthreads();
    for (int off = 1; off < 256; off <<= 1) {
        int t = (tid >= off) ? s[tid - off] : 0;
        __syncthreads();
        s[tid] += t;
        __syncthreads();
    }
    if (tid < nbk) { int ex = s[tid] - v; boff[tid] = ex; bcur[tid] = ex; }
    if (tid == 0) boff[nbk] = E;
}

__global__ __launch_bounds__(256) void bucket_scatter(const int* __restrict__ src,
                                                      const int* __restrict__ dst,
                                                      int* __restrict__ bcur,
                                                      uint2* __restrict__ ebuf, int E, int nbk) {
    __shared__ uint2 pairs[CHUNK];
    __shared__ int lcnt[256], lpos[256], delta[256], s[256];
    int tid = threadIdx.x;
    int base = blockIdx.x * CHUNK;
    int cnt = min(CHUNK, E - base);
    lcnt[tid] = 0;
    __syncthreads();
    for (int i = tid; i < cnt; i += 256)
        atomicAdd(&lcnt[dst[base + i] >> BSH], 1);
    __syncthreads();
    int v = lcnt[tid];
    s[tid] = v;
    __syncthreads();
    for (int off = 1; off < 256; off <<= 1) {
        int t = (tid >= off) ? s[tid - off] : 0;
        __syncthreads();
        s[tid] += t;
        __syncthreads();
    }
    lpos[tid] = s[tid] - v;
    if (tid < nbk && v) {
        int gb = atomicAdd(&bcur[tid], v);
        delta[tid] = gb - (s[tid] - v);
    }
    lcnt[tid] = 0;
    __syncthreads();
    for (int i = tid; i < cnt; i += 256) {
        int d = dst[base + i], sv = src[base + i];
        int b = d >> BSH;
        int idx = lpos[b] + atomicAdd(&lcnt[b], 1);
        pairs[idx] = make_uint2((unsigned)sv, (unsigned)d);
    }
    __syncthreads();
    for (int i = tid; i < cnt; i += 256) {
        uint2 p = pairs[i];
        ebuf[delta[p.y >> BSH] + i] = p;      // bucket-ordered runs -> coalesced
    }
}

__global__ __launch_bounds__(512) void csr_finalize(const uint2* __restrict__ ebuf,
                                                    const int* __restrict__ boff,
                                                    int* __restrict__ rowptr,
                                                    float* __restrict__ dinv,
                                                    int* __restrict__ col, int N, int E) {
    __shared__ int cnt[512], s[512];
    int tid = threadIdx.x;
    int b = blockIdx.x;
    int d0 = b << BSH;
    int beg = boff[b], end = boff[b + 1];
    cnt[tid] = 0;
    __syncthreads();
    for (int j = beg + tid; j < end; j += 512)
        atomicAdd(&cnt[ebuf[j].y - d0], 1);
    __syncthreads();
    int v = cnt[tid];
    s[tid] = v;
    __syncthreads();
    for (int off = 1; off < 512; off <<= 1) {
        int t = (tid >= off) ? s[tid - off] : 0;
        __syncthreads();
        s[tid] += t;
        __syncthreads();
    }
    int ex = s[tid] - v;
    int d = d0 + tid;
    if (d < N) {
        rowptr[d] = beg + ex;
        dinv[d] = rsqrtf((float)(v + 1));     // +1 self loop
    }
    if (b == 0 && tid == 0) rowptr[N] = E;
    __syncthreads();
    cnt[tid] = ex;
    __syncthreads();
    for (int j = beg + tid; j < end; j += 512) {
        uint2 p = ebuf[j];
        int pos = beg + atomicAdd(&cnt[p.y - d0], 1);
        col[pos] = (int)p.x;                  // writes stay in this block's region
    }
}

// -------- weight prep: cast + transpose to bf16 [C][K]; Wp padded to 48 cols --------

__global__ void prep_weights(const float* __restrict__ Wpre, const float* __restrict__ W1,
                             const float* __restrict__ W2, const float* __restrict__ Wp,
                             unsigned short* __restrict__ WpreT,
                             unsigned short* __restrict__ W1T,
                             unsigned short* __restrict__ W2T,
                             unsigned short* __restrict__ WpT) {
    int id = blockIdx.x * blockDim.x + threadIdx.x;   // 71680 total
    if (id < 32768) {                                  // Wpre [256][128] -> [128][256]
        int k = id >> 7, c = id & 127;
        WpreT[c * 256 + k] = f2bf(Wpre[id]);
    } else if (id < 49152) {
        int t = id - 32768; int k = t >> 7, c = t & 127;
        W1T[c * 128 + k] = f2bf(W1[t]);
    } else if (id < 65536) {
        int t = id - 49152; int k = t >> 7, c = t & 127;
        W2T[c * 128 + k] = f2bf(W2[t]);
    } else if (id < 71680) {                           // Wp [128][40] -> [48][128], zero-pad
        int t = id - 65536; int c = t >> 7, k = t & 127;
        WpT[c * 128 + k] = (c < 40) ? f2bf(Wp[k * 40 + c]) : (unsigned short)0;
    }
}

// ---------------- MFMA GEMM: [N,K] x Wt[128][K] -> bf16 [N,128] ----------------

template <int K, bool AFLOAT, bool BIAS>
__global__ __launch_bounds__(256) void gemm_mfma(const void* __restrict__ Av,
                                                 const unsigned short* __restrict__ Wt,
                                                 const float* __restrict__ bias,
                                                 unsigned short* __restrict__ out,
                                                 int N) {
    __shared__ unsigned short Ws[128 * 136];
    int tid = threadIdx.x;
    int lane = tid & 63;
    int w = tid >> 6;
    int l15 = lane & 15;
    int lk = lane >> 4;                // 0..3
    int wrow = blockIdx.x * 128 + w * 32;

    f32x4 acc[2][8];
    #pragma unroll
    for (int mt = 0; mt < 2; mt++)
        #pragma unroll
        for (int nt = 0; nt < 8; nt++)
            acc[mt][nt] = (f32x4)0.f;

    #pragma unroll
    for (int c = 0; c < K / 128; ++c) {
        __syncthreads();
        #pragma unroll
        for (int i = 0; i < 8; i++) {
            int v = tid + i * 256;
            int rowc = v >> 4, c16 = v & 15;
            *(ushort8*)&Ws[rowc * 136 + c16 * 8] =
                *(const ushort8*)&Wt[(size_t)rowc * K + c * 128 + c16 * 8];
        }
        __syncthreads();

        bf16x8 af[2][4];
        #pragma unroll
        for (int mt = 0; mt < 2; mt++) {
            int r = wrow + mt * 16 + l15;
            bool ok = r < N;
            #pragma unroll
            for (int ks = 0; ks < 4; ks++) {
                int k = c * 128 + ks * 32 + lk * 8;
                if (AFLOAT) {
                    const float* ap = (const float*)Av + (size_t)r * K + k;
                    float4 x0 = make_float4(0.f, 0.f, 0.f, 0.f), x1 = x0;
                    if (ok) { x0 = *(const float4*)ap; x1 = *(const float4*)(ap + 4); }
                    ushort8 u;
                    u[0] = f2bf(x0.x); u[1] = f2bf(x0.y); u[2] = f2bf(x0.z); u[3] = f2bf(x0.w);
                    u[4] = f2bf(x1.x); u[5] = f2bf(x1.y); u[6] = f2bf(x1.z); u[7] = f2bf(x1.w);
                    af[mt][ks] = __builtin_bit_cast(bf16x8, u);
                } else {
                    const unsigned short* ap = (const unsigned short*)Av + (size_t)r * K + k;
                    ushort8 u = {};
                    if (ok) u = *(const ushort8*)ap;
                    af[mt][ks] = __builtin_bit_cast(bf16x8, u);
                }
            }
        }

        #pragma unroll
        for (int nt = 0; nt < 8; nt++) {
            bf16x8 bfr[4];
            #pragma unroll
            for (int ks = 0; ks < 4; ks++) {
                ushort8 u = *(const ushort8*)&Ws[(nt * 16 + l15) * 136 + ks * 32 + lk * 8];
                bfr[ks] = __builtin_bit_cast(bf16x8, u);
            }
            #pragma unroll
            for (int ks = 0; ks < 4; ks++) {
                acc[0][nt] = __builtin_amdgcn_mfma_f32_16x16x32_bf16(af[0][ks], bfr[ks], acc[0][nt], 0, 0, 0);
                acc[1][nt] = __builtin_amdgcn_mfma_f32_16x16x32_bf16(af[1][ks], bfr[ks], acc[1][nt], 0, 0, 0);
            }
        }
    }

    #pragma unroll
    for (int nt = 0; nt < 8; nt++) {
        int colc = nt * 16 + l15;
        float bv = BIAS ? bias[colc] : 0.f;
        #pragma unroll
        for (int mt = 0; mt < 2; mt++) {
            #pragma unroll
            for (int j = 0; j < 4; j++) {
                int r = wrow + mt * 16 + lk * 4 + j;
                if (r < N)
                    out[(size_t)r * 128 + colc] = f2bf(acc[mt][nt][j] + bv);
            }
        }
    }
}

// ------------- CSR gather-aggregate: wave/node, 4 groups x 2-deep pipeline -------------

__global__ __launch_bounds__(256) void aggregate_bf16(const unsigned short* __restrict__ t,
                                                      const int* __restrict__ rowptr,
                                                      const int* __restrict__ col,
                                                      const float* __restrict__ dinv,
                                                      const float* __restrict__ bias,
                                                      unsigned short* __restrict__ out,
                                                      int N) {
    int gid = blockIdx.x * blockDim.x + threadIdx.x;
    int wid = gid >> 6;          // node
    if (wid >= N) return;
    int lane = threadIdx.x & 63;
    int g  = lane >> 4;          // edge group 0..3
    int sl = lane & 15;          // covers cols sl*8 .. sl*8+7

    float dv = dinv[wid];
    int beg = rowptr[wid], end = rowptr[wid + 1];

    float acc[8];
    #pragma unroll
    for (int i = 0; i < 8; i++) acc[i] = 0.f;

    if (g == 0) {
        ushort8 s = *(const ushort8*)&t[(size_t)wid * 128 + sl * 8];
        float w0 = dv * dv;
        #pragma unroll
        for (int i = 0; i < 8; i++) acc[i] = w0 * bf2f(s[i]);
    }

    int e = beg + g;
    int u0 = (e < end) ? col[e] : 0;
    int u1 = (e + 4 < end) ? col[e + 4] : 0;
    while (e < end) {
        float du0 = dinv[u0];
        ushort8 m0 = *(const ushort8*)&t[(size_t)u0 * 128 + sl * 8];
        float du1 = dinv[u1];
        ushort8 m1 = *(const ushort8*)&t[(size_t)u1 * 128 + sl * 8];
        int u2 = (e + 8  < end) ? col[e + 8]  : 0;
        int u3 = (e + 12 < end) ? col[e + 12] : 0;
        float w0 = du0 * dv;
        #pragma unroll
        for (int i = 0; i < 8; i++) acc[i] += w0 * bf2f(m0[i]);
        float w1 = (e + 4 < end) ? du1 * dv : 0.f;
        #pragma unroll
        for (int i = 0; i < 8; i++) acc[i] += w1 * bf2f(m1[i]);
        u0 = u2; u1 = u3;
        e += 8;
    }

    // combine the 4 groups (lanes sl, sl+16, sl+32, sl+48)
    #pragma unroll
    for (int i = 0; i < 8; i++) {
        acc[i] += __shfl_xor(acc[i], 16);
        acc[i] += __shfl_xor(acc[i], 32);
    }

    if (g == 0) {
        float4 b0 = *(const float4*)&bias[sl * 8];
        float4 b1 = *(const float4*)&bias[sl * 8 + 4];
        float bb[8] = {b0.x, b0.y, b0.z, b0.w, b1.x, b1.y, b1.z, b1.w};
        ushort8 o;
        #pragma unroll
        for (int i = 0; i < 8; i++) o[i] = f2bf(fmaxf(acc[i] + bb[i], 0.f));
        *(ushort8*)&out[(size_t)wid * 128 + sl * 8] = o;
    }
}

// -------- fused post GEMM (MFMA, B in regs) + in-register log_softmax --------

__global__ __launch_bounds__(256) void post_mfma(const unsigned short* __restrict__ Xb,
                                                 const unsigned short* __restrict__ WpT,
                                                 const float* __restrict__ bp,
                                                 float* __restrict__ out, int N) {
    int tid = threadIdx.x;
    int lane = tid & 63;
    int w = tid >> 6;
    int l15 = lane & 15;
    int lk = lane >> 4;
    int wrow = blockIdx.x * 128 + w * 32;

    bf16x8 bfr[3][4];
    #pragma unroll
    for (int nt = 0; nt < 3; nt++)
        #pragma unroll
        for (int ks = 0; ks < 4; ks++)
            bfr[nt][ks] = __builtin_bit_cast(bf16x8,
                *(const ushort8*)&WpT[(size_t)(nt * 16 + l15) * 128 + ks * 32 + lk * 8]);

    float bv[3];
    #pragma unroll
    for (int nt = 0; nt < 3; nt++) {
        int c = nt * 16 + l15;
        bv[nt] = (c < NCLASS) ? bp[c] : 0.f;
    }

    f32x4 acc[2][3];
    #pragma unroll
    for (int mt = 0; mt < 2; mt++)
        #pragma unroll
        for (int nt = 0; nt < 3; nt++)
            acc[mt][nt] = (f32x4)0.f;

    #pragma unroll
    for (int mt = 0; mt < 2; mt++) {
        int r = wrow + mt * 16 + l15;
        bool ok = r < N;
        #pragma unroll
        for (int ks = 0; ks < 4; ks++) {
            ushort8 u = {};
            if (ok) u = *(const ushort8*)&Xb[(size_t)r * 128 + ks * 32 + lk * 8];
            bf16x8 af = __builtin_bit_cast(bf16x8, u);
            #pragma unroll
            for (int nt = 0; nt < 3; nt++)
                acc[mt][nt] = __builtin_amdgcn_mfma_f32_16x16x32_bf16(af, bfr[nt][ks], acc[mt][nt], 0, 0, 0);
        }
    }

    bool v2 = l15 < 8;   // tile 2 valid cols: 32..39
    #pragma unroll
    for (int mt = 0; mt < 2; mt++) {
        #pragma unroll
        for (int j = 0; j < 4; j++) {
            float a0 = acc[mt][0][j] + bv[0];
            float a1 = acc[mt][1][j] + bv[1];
            float a2 = v2 ? (acc[mt][2][j] + bv[2]) : -1e30f;
            float m = fmaxf(fmaxf(a0, a1), a2);
            m = fmaxf(m, __shfl_xor(m, 1));
            m = fmaxf(m, __shfl_xor(m, 2));
            m = fmaxf(m, __shfl_xor(m, 4));
            m = fmaxf(m, __shfl_xor(m, 8));
            float s = __expf(a0 - m) + __expf(a1 - m) + (v2 ? __expf(a2 - m) : 0.f);
            s += __shfl_xor(s, 1);
            s += __shfl_xor(s, 2);
            s += __shfl_xor(s, 4);
            s += __shfl_xor(s, 8);
            float lse = m + __logf(s);
            int r = wrow + mt * 16 + lk * 4 + j;
            if (r < N) {
                out[(size_t)r * 40 + l15]      = a0 - lse;
                out[(size_t)r * 40 + 16 + l15] = a1 - lse;
                if (v2) out[(size_t)r * 40 + 32 + l15] = a2 - lse;
            }
        }
    }
}

// ---------------- launch ----------------

extern "C" void kernel_launch(void* const* d_in, const int* in_sizes, int n_in,
                              void* d_out, int out_size, void* d_ws, size_t ws_size,
                              hipStream_t stream) {
    const int N = in_sizes[0] / NFEAT;   // 100000
    const int E = in_sizes[1] / 2;       // 1600000
    const int nbk = (N + (1 << BSH) - 1) >> BSH;   // 196 buckets

    const float* x     = (const float*)d_in[0];
    const int*   ei    = (const int*)d_in[1];
    const int*   src   = ei;
    const int*   dst   = ei + E;
    const float* W_pre = (const float*)d_in[2];
    const float* b_pre = (const float*)d_in[3];
    const float* W1    = (const float*)d_in[4];
    const float* b1    = (const float*)d_in[5];
    const float* W2    = (const float*)d_in[6];
    const float* b2    = (const float*)d_in[7];
    const float* Wp    = (const float*)d_in[8];
    const float* bp    = (const float*)d_in[9];
    float* out = (float*)d_out;

    char* ws = (char*)d_ws;
    size_t off = 0;
    auto alloc = [&](size_t bytes) -> void* {
        off = (off + 255) & ~(size_t)255;
        void* p = ws + off;
        off += bytes;
        return p;
    };
    int*   rowptr  = (int*)alloc((size_t)(N + 1) * 4);
    float* dinv    = (float*)alloc((size_t)N * 4);
    int*   colbuf  = (int*)alloc((size_t)E * 4);
    uint2* ebuf    = (uint2*)alloc((size_t)E * 8);
    int*   bcnt    = (int*)alloc(256 * 4);
    int*   boff    = (int*)alloc(257 * 4);
    int*   bcur    = (int*)alloc(256 * 4);
    unsigned short* WpreT = (unsigned short*)alloc((size_t)NFEAT * NHID * 2);
    unsigned short* W1T   = (unsigned short*)alloc((size_t)NHID * NHID * 2);
    unsigned short* W2T   = (unsigned short*)alloc((size_t)NHID * NHID * 2);
    unsigned short* WpT   = (unsigned short*)alloc((size_t)48 * NHID * 2);
    unsigned short* bufA  = (unsigned short*)alloc((size_t)N * NHID * 2);
    unsigned short* bufB  = (unsigned short*)alloc((size_t)N * NHID * 2);
    (void)ws_size;

    int gsc = (E + CHUNK - 1) / CHUNK;          // scatter blocks
    int gm  = (N + 127) / 128;                  // mfma gemm grid
    int ga  = (int)(((size_t)N * 64 + 255) / 256);

    // 1. CSR build (bucketed) + weight prep
    hipMemsetAsync(bcnt, 0, 256 * 4, stream);
    bucket_count<<<128, 256, 0, stream>>>(dst, bcnt, E, nbk);
    bucket_scan<<<1, 256, 0, stream>>>(bcnt, boff, bcur, nbk, E);
    bucket_scatter<<<gsc, 256, 0, stream>>>(src, dst, bcur, ebuf, E, nbk);
    csr_finalize<<<nbk, 512, 0, stream>>>(ebuf, boff, rowptr, dinv, colbuf, N, E);
    prep_weights<<<280, 256, 0, stream>>>(W_pre, W1, W2, Wp, WpreT, W1T, W2T, WpT);

    // 2. h0 = x @ W_pre + b_pre  (fp32 in, bf16 out)
    gemm_mfma<NFEAT, true, true><<<gm, 256, 0, stream>>>(x, WpreT, b_pre, bufA, N);

    // 3. conv1
    gemm_mfma<NHID, false, false><<<gm, 256, 0, stream>>>(bufA, W1T, nullptr, bufB, N);
    aggregate_bf16<<<ga, 256, 0, stream>>>(bufB, rowptr, colbuf, dinv, b1, bufA, N);

    // 4. conv2
    gemm_mfma<NHID, false, false><<<gm, 256, 0, stream>>>(bufA, W2T, nullptr, bufB, N);
    aggregate_bf16<<<ga, 256, 0, stream>>>(bufB, rowptr, colbuf, dinv, b2, bufA, N);

    // 5. logits + log_softmax (MFMA, no LDS)
    post_mfma<<<gm, 256, 0, stream>>>(bufA, WpT, bp, out, N);
}

// Round 10
// 421.135 us; speedup vs baseline: 2.1438x; 1.0357x over previous
//
#include <hip/hip_runtime.h>
#include <hip/hip_bf16.h>

// GCN: 2-layer GCNConv with symmetric norm + self loops.
// N=100000 nodes, F=256, H=128, C=40, E=1600000 edges.
//
// Round 7 (resubmit x3 after infra failures):
//  - FOLD: t1 = x@(W_pre@W1) + b_pre@W1  (aggregation commutes with the
//    linear map; no nonlinearity between pre-linear and conv1 transform)
//    -> one K=128 GEMM + 51MB of h0 traffic eliminated. fuse_weights builds
//    Wc^T (bf16 [128][256]) and bc on device.
//  - gemm_mfma restructured: XOR-swizzled W LDS (conflict-free ds_read_b128),
//    batched fp32 A loads, LDS-transpose epilogue (ushort8 stores, 64B runs).
//  - CSR bucketed sort, aggregate, post_mfma unchanged from round 6.

#define NFEAT 256
#define NHID  128
#define NCLASS 40

#define BSH   9              // 512 dsts per bucket
#define CHUNK 8192           // edges staged per scatter block

typedef __attribute__((ext_vector_type(8))) __bf16 bf16x8;
typedef __attribute__((ext_vector_type(4))) float f32x4;
typedef __attribute__((ext_vector_type(8))) unsigned short ushort8;

__device__ __forceinline__ unsigned short f2bf(float f) {
    unsigned int u = __builtin_bit_cast(unsigned int, f);
    u = (u + 0x7FFF + ((u >> 16) & 1)) >> 16;   // RNE
    return (unsigned short)u;
}
__device__ __forceinline__ float bf2f(unsigned short h) {
    unsigned int u = ((unsigned int)h) << 16;
    return __builtin_bit_cast(float, u);
}

// ---------------- CSR build (bucketed) ----------------

__global__ __launch_bounds__(256) void bucket_count(const int* __restrict__ dst,
                                                    int* __restrict__ bcnt, int E, int nbk) {
    __shared__ int h[256];
    int tid = threadIdx.x;
    h[tid] = 0;
    __syncthreads();
    for (int e = blockIdx.x * 256 + tid; e < E; e += gridDim.x * 256)
        atomicAdd(&h[dst[e] >> BSH], 1);
    __syncthreads();
    if (tid < nbk && h[tid]) atomicAdd(&bcnt[tid], h[tid]);
}

__global__ __launch_bounds__(256) void bucket_scan(const int* __restrict__ bcnt,
                                                   int* __restrict__ boff,
                                                   int* __restrict__ bcur, int nbk, int E) {
    __shared__ int s[256];
    int tid = threadIdx.x;
    int v = (tid < nbk) ? bcnt[tid] : 0;
    s[tid] = v;
    __syncthreads();
    for (int off = 1; off < 256; off <<= 1) {
        int t = (tid >= off) ? s[tid - off] : 0;
        __syncthreads();
        s[tid] += t;
        __syncthreads();
    }
    if (tid < nbk) { int ex = s[tid] - v; boff[tid] = ex; bcur[tid] = ex; }
    if (tid == 0) boff[nbk] = E;
}

__global__ __launch_bounds__(256) void bucket_scatter(const int* __restrict__ src,
                                                      const int* __restrict__ dst,
                                                      int* __restrict__ bcur,
                                                      uint2* __restrict__ ebuf, int E, int nbk) {
    __shared__ uint2 pairs[CHUNK];
    __shared__ int lcnt[256], lpos[256], delta[256], s[256];
    int tid = threadIdx.x;
    int base = blockIdx.x * CHUNK;
    int cnt = min(CHUNK, E - base);
    lcnt[tid] = 0;
    __syncthreads();
    for (int i = tid; i < cnt; i += 256)
        atomicAdd(&lcnt[dst[base + i] >> BSH], 1);
    __syncthreads();
    int v = lcnt[tid];
    s[tid] = v;
    __syncthreads();
    for (int off = 1; off < 256; off <<= 1) {
        int t = (tid >= off) ? s[tid - off] : 0;
        __syncthreads();
        s[tid] += t;
        __syncthreads();
    }
    lpos[tid] = s[tid] - v;
    if (tid < nbk && v) {
        int gb = atomicAdd(&bcur[tid], v);
        delta[tid] = gb - (s[tid] - v);
    }
    lcnt[tid] = 0;
    __syncthreads();
    for (int i = tid; i < cnt; i += 256) {
        int d = dst[base + i], sv = src[base + i];
        int b = d >> BSH;
        int idx = lpos[b] + atomicAdd(&lcnt[b], 1);
        pairs[idx] = make_uint2((unsigned)sv, (unsigned)d);
    }
    __syncthreads();
    for (int i = tid; i < cnt; i += 256) {
        uint2 p = pairs[i];
        ebuf[delta[p.y >> BSH] + i] = p;      // bucket-ordered runs -> coalesced
    }
}

__global__ __launch_bounds__(512) void csr_finalize(const uint2* __restrict__ ebuf,
                                                    const int* __restrict__ boff,
                                                    int* __restrict__ rowptr,
                                                    float* __restrict__ dinv,
                                                    int* __restrict__ col, int N, int E) {
    __shared__ int cnt[512], s[512];
    int tid = threadIdx.x;
    int b = blockIdx.x;
    int d0 = b << BSH;
    int beg = boff[b], end = boff[b + 1];
    cnt[tid] = 0;
    __syncthreads();
    for (int j = beg + tid; j < end; j += 512)
        atomicAdd(&cnt[ebuf[j].y - d0], 1);
    __syncthreads();
    int v = cnt[tid];
    s[tid] = v;
    __syncthreads();
    for (int off = 1; off < 512; off <<= 1) {
        int t = (tid >= off) ? s[tid - off] : 0;
        __syncthreads();
        s[tid] += t;
        __syncthreads();
    }
    int ex = s[tid] - v;
    int d = d0 + tid;
    if (d < N) {
        rowptr[d] = beg + ex;
        dinv[d] = rsqrtf((float)(v + 1));     // +1 self loop
    }
    if (b == 0 && tid == 0) rowptr[N] = E;
    __syncthreads();
    cnt[tid] = ex;
    __syncthreads();
    for (int j = beg + tid; j < end; j += 512) {
        uint2 p = ebuf[j];
        int pos = beg + atomicAdd(&cnt[p.y - d0], 1);
        col[pos] = (int)p.x;                  // writes stay in this block's region
    }
}

// -------- fuse_weights: Wc = W_pre @ W1 (bf16 W1), out WcT bf16 [128][256]; bc = b_pre @ W1 --------

__global__ __launch_bounds__(256) void fuse_weights(const float* __restrict__ Wpre,
                                                    const float* __restrict__ W1,
                                                    const float* __restrict__ bpre,
                                                    unsigned short* __restrict__ WcT,
                                                    float* __restrict__ bc) {
    __shared__ unsigned short W1s[128 * 128];   // bf16 copy of W1, 32KB
    int tid = threadIdx.x;
    for (int i = tid; i < 4096; i += 256) {
        float4 a = ((const float4*)W1)[i];
        W1s[i * 4 + 0] = f2bf(a.x);
        W1s[i * 4 + 1] = f2bf(a.y);
        W1s[i * 4 + 2] = f2bf(a.z);
        W1s[i * 4 + 3] = f2bf(a.w);
    }
    __syncthreads();
    int b = blockIdx.x;
    if (b < 128) {
        int k = b * 2 + (tid >> 7);        // 0..255
        int c = tid & 127;
        const float* wrow = Wpre + (size_t)k * 128;
        float acc = 0.f;
        #pragma unroll 8
        for (int j = 0; j < 128; j++) acc += wrow[j] * bf2f(W1s[j * 128 + c]);
        WcT[c * 256 + k] = f2bf(acc);
    } else if (tid < 128) {
        float acc = 0.f;
        for (int j = 0; j < 128; j++) acc += bpre[j] * bf2f(W1s[j * 128 + tid]);
        bc[tid] = acc;
    }
}

// -------- weight prep: W2 -> bf16 [128][128] transposed; Wp -> bf16 [48][128] padded --------

__global__ void prep_weights(const float* __restrict__ W2, const float* __restrict__ Wp,
                             unsigned short* __restrict__ W2T,
                             unsigned short* __restrict__ WpT) {
    int id = blockIdx.x * blockDim.x + threadIdx.x;   // 22528 total
    if (id < 16384) {                                  // W2 [128][128] -> [128][128]^T
        int k = id >> 7, c = id & 127;
        W2T[c * 128 + k] = f2bf(W2[id]);
    } else if (id < 22528) {                           // Wp [128][40] -> [48][128], zero-pad
        int t = id - 16384; int c = t >> 7, k = t & 127;
        WpT[c * 128 + k] = (c < 40) ? f2bf(Wp[k * 40 + c]) : (unsigned short)0;
    }
}

// ---------------- MFMA GEMM: [N,K] x Wt[128][K] -> bf16 [N,128] ----------------
// block = 256 thr (4 waves); each wave 32 rows (2 mtiles of 16); block 128 rows.
// W tile in LDS, linear [128 rows][256 B] with XOR swizzle byte^=((row&7)<<4):
// B-frag ds_read_b128 then hits all 8 bank-groups evenly (optimal 8-phase).
// Epilogue: per-wave LDS transpose (stride 136 shorts) -> ushort8 stores.

template <int K, bool AFLOAT, bool BIAS>
__global__ __launch_bounds__(256) void gemm_mfma(const void* __restrict__ Av,
                                                 const unsigned short* __restrict__ Wt,
                                                 const float* __restrict__ bias,
                                                 unsigned short* __restrict__ out,
                                                 int N) {
    __shared__ unsigned short Ws[16384];   // 32KB: W tile (swizzled) / epilogue scratch
    int tid = threadIdx.x;
    int lane = tid & 63;
    int w = tid >> 6;
    int l15 = lane & 15;
    int lk = lane >> 4;                // 0..3
    int wrow = blockIdx.x * 128 + w * 32;

    f32x4 acc[2][8];
    #pragma unroll
    for (int mt = 0; mt < 2; mt++)
        #pragma unroll
        for (int nt = 0; nt < 8; nt++)
            acc[mt][nt] = (f32x4)0.f;

    #pragma unroll
    for (int c = 0; c < K / 128; ++c) {
        __syncthreads();
        // stage W chunk [128 rows][128 shorts], XOR-swizzled
        #pragma unroll
        for (int i = 0; i < 8; i++) {
            int v = tid + i * 256;
            int rowc = v >> 4, c16 = v & 15;
            int byte = (rowc * 256 + c16 * 16) ^ ((rowc & 7) << 4);
            *(ushort8*)((char*)Ws + byte) =
                *(const ushort8*)&Wt[(size_t)rowc * K + c * 128 + c16 * 8];
        }
        __syncthreads();

        // A fragments (batched loads per mt)
        bf16x8 af[2][4];
        #pragma unroll
        for (int mt = 0; mt < 2; mt++) {
            int r = wrow + mt * 16 + l15;
            bool ok = r < N;
            if (AFLOAT) {
                float4 raw[4][2];
                const float* ap0 = (const float*)Av + (size_t)r * K + c * 128 + lk * 8;
                float4 z = make_float4(0.f, 0.f, 0.f, 0.f);
                #pragma unroll
                for (int ks = 0; ks < 4; ks++) {
                    raw[ks][0] = ok ? *(const float4*)(ap0 + ks * 32) : z;
                    raw[ks][1] = ok ? *(const float4*)(ap0 + ks * 32 + 4) : z;
                }
                #pragma unroll
                for (int ks = 0; ks < 4; ks++) {
                    ushort8 u;
                    u[0] = f2bf(raw[ks][0].x); u[1] = f2bf(raw[ks][0].y);
                    u[2] = f2bf(raw[ks][0].z); u[3] = f2bf(raw[ks][0].w);
                    u[4] = f2bf(raw[ks][1].x); u[5] = f2bf(raw[ks][1].y);
                    u[6] = f2bf(raw[ks][1].z); u[7] = f2bf(raw[ks][1].w);
                    af[mt][ks] = __builtin_bit_cast(bf16x8, u);
                }
            } else {
                const unsigned short* ap = (const unsigned short*)Av + (size_t)r * K + c * 128 + lk * 8;
                #pragma unroll
                for (int ks = 0; ks < 4; ks++) {
                    ushort8 u = {};
                    if (ok) u = *(const ushort8*)(ap + ks * 32);
                    af[mt][ks] = __builtin_bit_cast(bf16x8, u);
                }
            }
        }

        #pragma unroll
        for (int nt = 0; nt < 8; nt++) {
            bf16x8 bfr[4];
            #pragma unroll
            for (int ks = 0; ks < 4; ks++) {
                int row = nt * 16 + l15;
                int byte = (row * 256 + ks * 64 + lk * 16) ^ ((row & 7) << 4);
                bfr[ks] = *(bf16x8*)((char*)Ws + byte);
            }
            #pragma unroll
            for (int ks = 0; ks < 4; ks++) {
                acc[0][nt] = __builtin_amdgcn_mfma_f32_16x16x32_bf16(af[0][ks], bfr[ks], acc[0][nt], 0, 0, 0);
                acc[1][nt] = __builtin_amdgcn_mfma_f32_16x16x32_bf16(af[1][ks], bfr[ks], acc[1][nt], 0, 0, 0);
            }
        }
    }

    // ---- epilogue: per-wave LDS transpose -> ushort8 stores (64B row runs) ----
    __syncthreads();                        // all W-frag reads done before scratch reuse
    unsigned short* scr = Ws + w * 2176;    // 16 rows x 136 shorts per wave
    int srow = lane >> 2;                   // 0..15
    int bch  = lane & 3;                    // 0..3
    #pragma unroll
    for (int mt = 0; mt < 2; mt++) {
        #pragma unroll
        for (int nt = 0; nt < 8; nt++) {
            float bv = BIAS ? bias[nt * 16 + l15] : 0.f;
            #pragma unroll
            for (int j = 0; j < 4; j++)
                scr[(lk * 4 + j) * 136 + nt * 16 + l15] = f2bf(acc[mt][nt][j] + bv);
        }
        __syncthreads();
        int grow = wrow + mt * 16 + srow;
        #pragma unroll
        for (int it = 0; it < 4; it++) {
            int chunk = bch + it * 4;       // 0..15
            ushort8 v = *(ushort8*)&scr[srow * 136 + chunk * 8];
            if (grow < N)
                *(ushort8*)&out[(size_t)grow * 128 + chunk * 8] = v;
        }
        __syncthreads();
    }
}

// ------------- CSR gather-aggregate: wave/node, 4 groups x 2-deep pipeline -------------

__global__ __launch_bounds__(256) void aggregate_bf16(const unsigned short* __restrict__ t,
                                                      const int* __restrict__ rowptr,
                                                      const int* __restrict__ col,
                                                      const float* __restrict__ dinv,
                                                      const float* __restrict__ bias,
                                                      unsigned short* __restrict__ out,
                                                      int N) {
    int gid = blockIdx.x * blockDim.x + threadIdx.x;
    int wid = gid >> 6;          // node
    if (wid >= N) return;
    int lane = threadIdx.x & 63;
    int g  = lane >> 4;          // edge group 0..3
    int sl = lane & 15;          // covers cols sl*8 .. sl*8+7

    float dv = dinv[wid];
    int beg = rowptr[wid], end = rowptr[wid + 1];

    float acc[8];
    #pragma unroll
    for (int i = 0; i < 8; i++) acc[i] = 0.f;

    if (g == 0) {
        ushort8 s = *(const ushort8*)&t[(size_t)wid * 128 + sl * 8];
        float w0 = dv * dv;
        #pragma unroll
        for (int i = 0; i < 8; i++) acc[i] = w0 * bf2f(s[i]);
    }

    int e = beg + g;
    int u0 = (e < end) ? col[e] : 0;
    int u1 = (e + 4 < end) ? col[e + 4] : 0;
    while (e < end) {
        float du0 = dinv[u0];
        ushort8 m0 = *(const ushort8*)&t[(size_t)u0 * 128 + sl * 8];
        float du1 = dinv[u1];
        ushort8 m1 = *(const ushort8*)&t[(size_t)u1 * 128 + sl * 8];
        int u2 = (e + 8  < end) ? col[e + 8]  : 0;
        int u3 = (e + 12 < end) ? col[e + 12] : 0;
        float w0 = du0 * dv;
        #pragma unroll
        for (int i = 0; i < 8; i++) acc[i] += w0 * bf2f(m0[i]);
        float w1 = (e + 4 < end) ? du1 * dv : 0.f;
        #pragma unroll
        for (int i = 0; i < 8; i++) acc[i] += w1 * bf2f(m1[i]);
        u0 = u2; u1 = u3;
        e += 8;
    }

    // combine the 4 groups (lanes sl, sl+16, sl+32, sl+48)
    #pragma unroll
    for (int i = 0; i < 8; i++) {
        acc[i] += __shfl_xor(acc[i], 16);
        acc[i] += __shfl_xor(acc[i], 32);
    }

    if (g == 0) {
        float4 b0 = *(const float4*)&bias[sl * 8];
        float4 b1 = *(const float4*)&bias[sl * 8 + 4];
        float bb[8] = {b0.x, b0.y, b0.z, b0.w, b1.x, b1.y, b1.z, b1.w};
        ushort8 o;
        #pragma unroll
        for (int i = 0; i < 8; i++) o[i] = f2bf(fmaxf(acc[i] + bb[i], 0.f));
        *(ushort8*)&out[(size_t)wid * 128 + sl * 8] = o;
    }
}

// -------- fused post GEMM (MFMA, B in regs) + in-register log_softmax --------

__global__ __launch_bounds__(256) void post_mfma(const unsigned short* __restrict__ Xb,
                                                 const unsigned short* __restrict__ WpT,
                                                 const float* __restrict__ bp,
                                                 float* __restrict__ out, int N) {
    int tid = threadIdx.x;
    int lane = tid & 63;
    int w = tid >> 6;
    int l15 = lane & 15;
    int lk = lane >> 4;
    int wrow = blockIdx.x * 128 + w * 32;

    bf16x8 bfr[3][4];
    #pragma unroll
    for (int nt = 0; nt < 3; nt++)
        #pragma unroll
        for (int ks = 0; ks < 4; ks++)
            bfr[nt][ks] = __builtin_bit_cast(bf16x8,
                *(const ushort8*)&WpT[(size_t)(nt * 16 + l15) * 128 + ks * 32 + lk * 8]);

    float bv[3];
    #pragma unroll
    for (int nt = 0; nt < 3; nt++) {
        int c = nt * 16 + l15;
        bv[nt] = (c < NCLASS) ? bp[c] : 0.f;
    }

    f32x4 acc[2][3];
    #pragma unroll
    for (int mt = 0; mt < 2; mt++)
        #pragma unroll
        for (int nt = 0; nt < 3; nt++)
            acc[mt][nt] = (f32x4)0.f;

    #pragma unroll
    for (int mt = 0; mt < 2; mt++) {
        int r = wrow + mt * 16 + l15;
        bool ok = r < N;
        #pragma unroll
        for (int ks = 0; ks < 4; ks++) {
            ushort8 u = {};
            if (ok) u = *(const ushort8*)&Xb[(size_t)r * 128 + ks * 32 + lk * 8];
            bf16x8 af = __builtin_bit_cast(bf16x8, u);
            #pragma unroll
            for (int nt = 0; nt < 3; nt++)
                acc[mt][nt] = __builtin_amdgcn_mfma_f32_16x16x32_bf16(af, bfr[nt][ks], acc[mt][nt], 0, 0, 0);
        }
    }

    bool v2 = l15 < 8;   // tile 2 valid cols: 32..39
    #pragma unroll
    for (int mt = 0; mt < 2; mt++) {
        #pragma unroll
        for (int j = 0; j < 4; j++) {
            float a0 = acc[mt][0][j] + bv[0];
            float a1 = acc[mt][1][j] + bv[1];
            float a2 = v2 ? (acc[mt][2][j] + bv[2]) : -1e30f;
            float m = fmaxf(fmaxf(a0, a1), a2);
            m = fmaxf(m, __shfl_xor(m, 1));
            m = fmaxf(m, __shfl_xor(m, 2));
            m = fmaxf(m, __shfl_xor(m, 4));
            m = fmaxf(m, __shfl_xor(m, 8));
            float s = __expf(a0 - m) + __expf(a1 - m) + (v2 ? __expf(a2 - m) : 0.f);
            s += __shfl_xor(s, 1);
            s += __shfl_xor(s, 2);
            s += __shfl_xor(s, 4);
            s += __shfl_xor(s, 8);
            float lse = m + __logf(s);
            int r = wrow + mt * 16 + lk * 4 + j;
            if (r < N) {
                out[(size_t)r * 40 + l15]      = a0 - lse;
                out[(size_t)r * 40 + 16 + l15] = a1 - lse;
                if (v2) out[(size_t)r * 40 + 32 + l15] = a2 - lse;
            }
        }
    }
}

// ---------------- launch ----------------

extern "C" void kernel_launch(void* const* d_in, const int* in_sizes, int n_in,
                              void* d_out, int out_size, void* d_ws, size_t ws_size,
                              hipStream_t stream) {
    const int N = in_sizes[0] / NFEAT;   // 100000
    const int E = in_sizes[1] / 2;       // 1600000
    const int nbk = (N + (1 << BSH) - 1) >> BSH;   // 196 buckets

    const float* x     = (const float*)d_in[0];
    const int*   ei    = (const int*)d_in[1];
    const int*   src   = ei;
    const int*   dst   = ei + E;
    const float* W_pre = (const float*)d_in[2];
    const float* b_pre = (const float*)d_in[3];
    const float* W1    = (const float*)d_in[4];
    const float* b1    = (const float*)d_in[5];
    const float* W2    = (const float*)d_in[6];
    const float* b2    = (const float*)d_in[7];
    const float* Wp    = (const float*)d_in[8];
    const float* bp    = (const float*)d_in[9];
    float* out = (float*)d_out;

    char* ws = (char*)d_ws;
    size_t off = 0;
    auto alloc = [&](size_t bytes) -> void* {
        off = (off + 255) & ~(size_t)255;
        void* p = ws + off;
        off += bytes;
        return p;
    };
    int*   rowptr  = (int*)alloc((size_t)(N + 1) * 4);
    float* dinv    = (float*)alloc((size_t)N * 4);
    int*   colbuf  = (int*)alloc((size_t)E * 4);
    uint2* ebuf    = (uint2*)alloc((size_t)E * 8);
    int*   bcnt    = (int*)alloc(256 * 4);
    int*   boff    = (int*)alloc(257 * 4);
    int*   bcur    = (int*)alloc(256 * 4);
    unsigned short* WcT  = (unsigned short*)alloc((size_t)NFEAT * NHID * 2);  // [128][256]
    float*          bc   = (float*)alloc(128 * 4);
    unsigned short* W2T  = (unsigned short*)alloc((size_t)NHID * NHID * 2);
    unsigned short* WpT  = (unsigned short*)alloc((size_t)48 * NHID * 2);
    unsigned short* bufA = (unsigned short*)alloc((size_t)N * NHID * 2);
    unsigned short* bufB = (unsigned short*)alloc((size_t)N * NHID * 2);
    (void)ws_size;

    int gsc = (E + CHUNK - 1) / CHUNK;          // scatter blocks
    int gm  = (N + 127) / 128;                  // mfma gemm grid
    int ga  = (int)(((size_t)N * 64 + 255) / 256);

    // 1. CSR build (bucketed) + weight prep/fold
    hipMemsetAsync(bcnt, 0, 256 * 4, stream);
    bucket_count<<<128, 256, 0, stream>>>(dst, bcnt, E, nbk);
    bucket_scan<<<1, 256, 0, stream>>>(bcnt, boff, bcur, nbk, E);
    bucket_scatter<<<gsc, 256, 0, stream>>>(src, dst, bcur, ebuf, E, nbk);
    csr_finalize<<<nbk, 512, 0, stream>>>(ebuf, boff, rowptr, dinv, colbuf, N, E);
    fuse_weights<<<129, 256, 0, stream>>>(W_pre, W1, b_pre, WcT, bc);
    prep_weights<<<88, 256, 0, stream>>>(W2, Wp, W2T, WpT);

    // 2. t1 = x @ Wc + bc  (folded pre-linear + conv1 transform)
    gemm_mfma<NFEAT, true, true><<<gm, 256, 0, stream>>>(x, WcT, bc, bufB, N);

    // 3. conv1 aggregate: h1 = relu(Agg(t1) + b1)
    aggregate_bf16<<<ga, 256, 0, stream>>>(bufB, rowptr, colbuf, dinv, b1, bufA, N);

    // 4. conv2: t2 = h1 @ W2 ; h2 = relu(Agg(t2) + b2)
    gemm_mfma<NHID, false, false><<<gm, 256, 0, stream>>>(bufA, W2T, nullptr, bufB, N);
    aggregate_bf16<<<ga, 256, 0, stream>>>(bufB, rowptr, colbuf, dinv, b2, bufA, N);

    // 5. logits + log_softmax (MFMA, no LDS)
    post_mfma<<<gm, 256, 0, stream>>>(bufA, WpT, bp, out, N);
}